// Round 1
// 2474.885 us; speedup vs baseline: 1.5084x; 1.5084x over previous
//
#include <hip/hip_runtime.h>
#include <hip/hip_bf16.h>

// Problem dims: BS=4, N=512, Bb=8, Cc=8, D=128, H=512, DP=64, G=64
// All inputs/outputs are float32 (per reference setup_inputs / return dtypes).
// Output element offsets (f32 elements, flat concat in return order)
constexpr long XO = 0;               // x_out   (4,512,64,128) 16777216
constexpr long ZO = 16777216;        // z       (4,512,64,64)   8388608
constexpr long ZH = 25165824;        // z_hat   (4,512,64,64)   8388608
constexpr long SO = 33554432;        // surprise(4,512,64)       131072
constexpr long KC = 33685504;        // k_cand  (...,128)      16777216
constexpr long VP = 50462720;        // v_post                 16777216
constexpr long GA = 67239936;        // gate                     131072
constexpr long QN = 67371008;        // q_nov                  16777216
constexpr long VC = 84148224;        // v_cand                 16777216
constexpr long WN = 100925440;       // w_nov                    131072

__device__ __forceinline__ float wred64(float v){
#pragma unroll
  for (int off = 32; off; off >>= 1) v += __shfl_xor(v, off, 64);
  return v;
}
__device__ __forceinline__ float wred32(float v){
#pragma unroll
  for (int off = 16; off; off >>= 1) v += __shfl_xor(v, off, 64);
  return v;
}
__device__ __forceinline__ float gelu_exact(float x){
  return x * 0.5f * (1.f + erff(x * 0.70710678118654752f));
}

// ---------------- Kernel A: latent LN + 8x8 attention + wo residual ------------
// one block per (s,n,b); 8 tokens (c=0..7) x 128 dims, contiguous 1024 elements.
__global__ __launch_bounds__(256) void attn_kernel(
    const float* __restrict__ x_col,
    const float* __restrict__ lat_g, const float* __restrict__ lat_b,
    const float* __restrict__ wq, const float* __restrict__ bq,
    const float* __restrict__ wk, const float* __restrict__ bk,
    const float* __restrict__ wv, const float* __restrict__ bv,
    const float* __restrict__ wo, const float* __restrict__ bo,
    float* __restrict__ xattn)
{
  // qs is reused as the attention-output buffer after scores are computed
  // (qs dead after the score matmul; saves 4 KB LDS vs a separate os_).
  __shared__ float xs[8][128], hs[8][128], qs[8][128], ks[8][128], vs[8][128];
  __shared__ float att[8][8];
  const int t = threadIdx.x;
  const long base = (long)blockIdx.x * 1024;

#pragma unroll
  for (int i = 0; i < 4; ++i) {
    int idx = t + i * 256;
    xs[idx >> 7][idx & 127] = x_col[base + idx];
  }
  __syncthreads();

  // LN over d=128, 32 threads per token
  {
    int c = t >> 5, j = t & 31;
    float s = 0.f, ss = 0.f;
#pragma unroll
    for (int m = 0; m < 4; ++m) { float v = xs[c][j + 32 * m]; s += v; ss += v * v; }
    s = wred32(s); ss = wred32(ss);
    float mean = s * (1.f / 128.f);
    float var  = ss * (1.f / 128.f) - mean * mean;
    float rsq  = rsqrtf(var + 1e-5f);
#pragma unroll
    for (int m = 0; m < 4; ++m) {
      int idx = j + 32 * m;
      hs[c][idx] = (xs[c][idx] - mean) * rsq * lat_g[idx] + lat_b[idx];
    }
  }
  __syncthreads();

  const int e  = t & 127;
  const int c0 = (t >> 7) * 4;   // tokens c0..c0+3

  // q,k,v projections (128x128 each), weight load amortized over 4 tokens
  {
    float aq[4] = {0,0,0,0}, ak[4] = {0,0,0,0}, av[4] = {0,0,0,0};
    for (int kk = 0; kk < 128; ++kk) {
      float wqv = wq[kk * 128 + e];
      float wkv = wk[kk * 128 + e];
      float wvv = wv[kk * 128 + e];
#pragma unroll
      for (int c4 = 0; c4 < 4; ++c4) {
        float hv = hs[c0 + c4][kk];
        aq[c4] += hv * wqv; ak[c4] += hv * wkv; av[c4] += hv * wvv;
      }
    }
    float bqv = bq[e], bkv = bk[e], bvv = bv[e];
#pragma unroll
    for (int c4 = 0; c4 < 4; ++c4) {
      qs[c0 + c4][e] = aq[c4] + bqv;
      ks[c0 + c4][e] = ak[c4] + bkv;
      vs[c0 + c4][e] = av[c4] + bvv;
    }
  }
  __syncthreads();

  // scores (8x8) * d^-0.5
  if (t < 64) {
    int c = t >> 3, e2 = t & 7;
    float acc = 0.f;
    for (int kk = 0; kk < 128; ++kk) acc += qs[c][kk] * ks[e2][kk];
    att[c][e2] = acc * 0.08838834764831845f;
  }
  __syncthreads();
  // softmax over e2
  if (t < 8) {
    float mx = -1e30f;
#pragma unroll
    for (int e2 = 0; e2 < 8; ++e2) mx = fmaxf(mx, att[t][e2]);
    float sum = 0.f, ex[8];
#pragma unroll
    for (int e2 = 0; e2 < 8; ++e2) { ex[e2] = expf(att[t][e2] - mx); sum += ex[e2]; }
    float inv = 1.f / sum;
#pragma unroll
    for (int e2 = 0; e2 < 8; ++e2) att[t][e2] = ex[e2] * inv;
  }
  __syncthreads();

  // o = att @ v   (written into qs, which is dead now)
#pragma unroll
  for (int c4 = 0; c4 < 4; ++c4) {
    int c = c0 + c4;
    float acc = 0.f;
#pragma unroll
    for (int e2 = 0; e2 < 8; ++e2) acc += att[c][e2] * vs[e2][e];
    qs[c][e] = acc;
  }
  __syncthreads();

  // out = x + o @ wo + bo
  {
    float ao[4] = {0,0,0,0};
    for (int kk = 0; kk < 128; ++kk) {
      float wov = wo[kk * 128 + e];
#pragma unroll
      for (int c4 = 0; c4 < 4; ++c4) ao[c4] += qs[c0 + c4][kk] * wov;
    }
    float bov = bo[e];
#pragma unroll
    for (int c4 = 0; c4 < 4; ++c4) {
      int c = c0 + c4;
      xattn[base + c * 128 + e] = xs[c][e] + ao[c4] + bov;
    }
  }
}

// ---------------- Kernel B: everything after attention --------------------------
// Grid reorder vs previous version: g = blockIdx.x >> 8, chunk = blockIdx.x & 255.
// Concurrently-resident blocks (~1000) now span ~4 groups -> live weight
// footprint ~3.4 MB (L2-resident) instead of all 64 groups (~55 MB, HBM thrash).
// LDS cut 47 KB -> 28 KB (no part/gn/zh/xo) + __launch_bounds__(256,4)
// -> 4 blocks/CU instead of 3.
__global__ __launch_bounds__(256, 4) void col_kernel(
    const float* __restrict__ zhp,
    const float* __restrict__ ln_g, const float* __restrict__ ln_b,
    const float* __restrict__ up_w, const float* __restrict__ up_b,
    const float* __restrict__ down_w, const float* __restrict__ down_b,
    const float* __restrict__ post_w, const float* __restrict__ post_b,
    const float* __restrict__ enc_w, const float* __restrict__ enc_b,
    const float* __restrict__ pred_w, const float* __restrict__ pred_b,
    const float* __restrict__ gain_w, const float* __restrict__ gain_b,
    float* __restrict__ out)
{
  __shared__ float xs[8][128];      // x_attn, updated in place to x_out after down
  __shared__ float zv[8][64];       // z
  __shared__ float dl[8][64];       // delta
  __shared__ float hn[8][128];      // group-LN output (gain applied in place)
  __shared__ float big[8][512];     // up output (gelu'd), then post projection

  const int t = threadIdx.x;
  const int g = blockIdx.x >> 8;          // 0..63
  const int chunk = blockIdx.x & 255;     // 0..255
  const long tok0 = (long)(chunk * 8) * 64 + g;    // token index for tk=0; stride 64 per tk

  // load x_attn (staged f32 in x_out slot)
#pragma unroll
  for (int i = 0; i < 4; ++i) {
    int idx = t + i * 256;               // 0..1023
    int tk = idx >> 7, o = idx & 127;
    xs[tk][o] = out[(tok0 + tk * 64) * 128 + o];
  }
  __syncthreads();

  // --- phase 1: enc (z, delta, surprise, gate) + group LN -> hn -------------
  {
    const int o = t & 63, tq = t >> 6;   // tq = wave id 0..3
    const float* w = enc_w + (long)g * (128 * 64) + o;
    float bias = enc_b[g * 64 + o];
#pragma unroll
    for (int pass = 0; pass < 2; ++pass) {
      int tk = tq + pass * 4;
      float zprev = zhp[(tok0 + tk * 64) * 64 + o];   // direct load, no LDS stage
      float acc = bias;
#pragma unroll 4
      for (int kk = 0; kk < 128; ++kk) acc += xs[tk][kk] * w[kk * 64];
      zv[tk][o] = acc;
      float d = acc - zprev;
      dl[tk][o] = d;
      out[ZO + (tok0 + tk * 64) * 64 + o] = acc;
      float s2 = wred64(d * d);
      if (o == 0) {
        float sur = sqrtf(s2);
        out[SO + tok0 + tk * 64] = sur;
        out[GA + tok0 + tk * 64] = fminf(sur, 1.f);  // clip(sur/1.0, 0, 1), sur>=0
      }
    }
  }
  // group LN (per token, 32 threads each) -> hn (gain applied next phase)
  {
    int tk = t >> 5, j = t & 31;
    float s = 0.f, ss = 0.f;
#pragma unroll
    for (int m = 0; m < 4; ++m) { float v = xs[tk][j + 32 * m]; s += v; ss += v * v; }
    s = wred32(s); ss = wred32(ss);
    float mean = s * (1.f / 128.f);
    float var  = ss * (1.f / 128.f) - mean * mean;
    float rsq  = rsqrtf(var + 1e-5f);
#pragma unroll
    for (int m = 0; m < 4; ++m) {
      int o = j + 32 * m;
      hn[tk][o] = (xs[tk][o] - mean) * rsq * ln_g[g * 128 + o] + ln_b[g * 128 + o];
    }
  }
  __syncthreads();

  // --- phase 2: pred (z_hat) + gain compute&apply into hn -------------------
  {
    const int o = t & 63, tq = t >> 6;
    const float* w = pred_w + (long)g * (64 * 64) + o;
    float bias = pred_b[g * 64 + o];
#pragma unroll
    for (int pass = 0; pass < 2; ++pass) {
      int tk = tq + pass * 4;
      float acc = bias;
#pragma unroll 4
      for (int kk = 0; kk < 64; ++kk) acc += zv[tk][kk] * w[kk * 64];
      out[ZH + (tok0 + tk * 64) * 64 + o] = acc;
    }
  }
  // gain = 1 + 0.1*tanh(delta @ gain_w[g] + gain_b); apply to hn in place
  {
    const int o = t & 127, tb = t >> 7;  // tokens tb, tb+2, tb+4, tb+6
    const float* w = gain_w + (long)g * (64 * 128) + o;
    float bias = gain_b[g * 128 + o];
    float acc[4] = {bias, bias, bias, bias};
#pragma unroll 4
    for (int kk = 0; kk < 64; ++kk) {
      float wv = w[kk * 128];
#pragma unroll
      for (int m = 0; m < 4; ++m) acc[m] += dl[tb + m * 2][kk] * wv;
    }
#pragma unroll
    for (int m = 0; m < 4; ++m)
      hn[tb + m * 2][o] *= 1.f + 0.1f * tanhf(acc[m]);
  }
  __syncthreads();

  // --- phase 3: up (128->512) + exact GELU ----------------------------------
  // thread t owns outputs 2t and 2t+1 -> aligned float2 weight loads
  {
    const float* w = up_w + (long)g * (128 * 512) + 2 * t;
    float b0 = up_b[g * 512 + 2 * t];
    float b1 = up_b[g * 512 + 2 * t + 1];
    float a0[8], a1[8];
#pragma unroll
    for (int tk = 0; tk < 8; ++tk) { a0[tk] = b0; a1[tk] = b1; }
#pragma unroll 4
    for (int kk = 0; kk < 128; ++kk) {
      float2 wv = *(const float2*)(w + (long)kk * 512);
#pragma unroll
      for (int tk = 0; tk < 8; ++tk) {
        float hv = hn[tk][kk];
        a0[tk] += hv * wv.x; a1[tk] += hv * wv.y;
      }
    }
#pragma unroll
    for (int tk = 0; tk < 8; ++tk) {
      float2 r; r.x = gelu_exact(a0[tk]); r.y = gelu_exact(a1[tk]);
      *(float2*)&big[tk][2 * t] = r;
    }
  }
  __syncthreads();

  // --- phase 4: down (512->128), full-K per thread, no cross-reduction ------
  // thread (o = t&127, th = t>>7) owns tokens th*4..th*4+3 at column o.
  {
    const int o = t & 127, th = t >> 7;
    const float* w = down_w + (long)g * (512 * 128) + o;
    float acc[4] = {0,0,0,0};
#pragma unroll 8
    for (int kk = 0; kk < 512; ++kk) {
      float wv = w[(long)kk * 128];
#pragma unroll
      for (int m = 0; m < 4; ++m) acc[m] += big[th * 4 + m][kk] * wv;
    }
    float bias = down_b[g * 128 + o];
#pragma unroll
    for (int m = 0; m < 4; ++m) {
      int tk = th * 4 + m;
      float v = xs[tk][o] + acc[m] + bias;
      xs[tk][o] = v;                                  // x_out in place
      out[XO + (tok0 + tk * 64) * 128 + o] = v;       // final x_out
    }
  }
  __syncthreads();

  // --- phase 5: post projection (128 -> 513) into big[][0..511] + w_nov ----
  {
    const float* w = post_w + (long)g * (128 * 513);
    float b0 = post_b[g * 513 + t];
    float b1 = post_b[g * 513 + t + 256];
    float a0[8], a1[8];
#pragma unroll
    for (int tk = 0; tk < 8; ++tk) { a0[tk] = b0; a1[tk] = b1; }
#pragma unroll 4
    for (int kk = 0; kk < 128; ++kk) {
      float w0 = w[kk * 513 + t];
      float w1 = w[kk * 513 + t + 256];
#pragma unroll
      for (int tk = 0; tk < 8; ++tk) {
        float xv = xs[tk][kk];
        a0[tk] += xv * w0; a1[tk] += xv * w1;
      }
    }
#pragma unroll
    for (int tk = 0; tk < 8; ++tk) { big[tk][t] = a0[tk]; big[tk][t + 256] = a1[tk]; }
  }
  // column 512 (novelty logit) + w_nov: wave0, 8 lanes per token
  if (t < 64) {
    int tk = t >> 3, j = t & 7;
    const float* w = post_w + (long)g * (128 * 513) + 512;
    float p = 0.f;
    for (int kk = j * 16; kk < j * 16 + 16; ++kk) p += xs[tk][kk] * w[(long)kk * 513];
    p += __shfl_xor(p, 1, 64);
    p += __shfl_xor(p, 2, 64);
    p += __shfl_xor(p, 4, 64);
    if (j == 0) {
      float nv = p + post_b[g * 513 + 512];
      out[WN + tok0 + tk * 64] = 1.f / (1.f + expf(-nv));
    }
  }
  __syncthreads();

  // --- phase 6: norms of k_pre / k_cand_raw; write 4 slice outputs ----------
  {
    int tk = t >> 5, j = t & 31;
    float s1 = 0.f, s2 = 0.f;
#pragma unroll
    for (int m = 0; m < 4; ++m) {
      float v1 = big[tk][j + 32 * m];
      float v2 = big[tk][256 + j + 32 * m];
      s1 += v1 * v1; s2 += v2 * v2;
    }
    s1 = wred32(s1); s2 = wred32(s2);
    float i1 = 1.f / fmaxf(sqrtf(s1), 1e-6f);
    float i2 = 1.f / fmaxf(sqrtf(s2), 1e-6f);
    long ob = (tok0 + tk * 64) * 128;
#pragma unroll
    for (int m = 0; m < 4; ++m) {
      int o = j + 32 * m;
      out[KC + ob + o] = big[tk][o] * i1;
      out[VP + ob + o] = big[tk][128 + o];
      out[QN + ob + o] = big[tk][256 + o] * i2;
      out[VC + ob + o] = big[tk][384 + o];
    }
  }
}

extern "C" void kernel_launch(void* const* d_in, const int* in_sizes, int n_in,
                              void* d_out, int out_size, void* d_ws, size_t ws_size,
                              hipStream_t stream) {
  (void)in_sizes; (void)n_in; (void)out_size; (void)d_ws; (void)ws_size;
  const float* x_col  = (const float*)d_in[0];
  const float* zhp    = (const float*)d_in[1];
  const float* ln_g   = (const float*)d_in[2];
  const float* ln_b   = (const float*)d_in[3];
  const float* up_w   = (const float*)d_in[4];
  const float* up_b   = (const float*)d_in[5];
  const float* down_w = (const float*)d_in[6];
  const float* down_b = (const float*)d_in[7];
  const float* lat_g  = (const float*)d_in[8];
  const float* lat_b  = (const float*)d_in[9];
  const float* wq     = (const float*)d_in[10];
  const float* bq     = (const float*)d_in[11];
  const float* wk     = (const float*)d_in[12];
  const float* bk     = (const float*)d_in[13];
  const float* wv     = (const float*)d_in[14];
  const float* bv     = (const float*)d_in[15];
  const float* wo     = (const float*)d_in[16];
  const float* bo     = (const float*)d_in[17];
  const float* post_w = (const float*)d_in[18];
  const float* post_b = (const float*)d_in[19];
  const float* enc_w  = (const float*)d_in[20];
  const float* enc_b  = (const float*)d_in[21];
  const float* pred_w = (const float*)d_in[22];
  const float* pred_b = (const float*)d_in[23];
  const float* gain_w = (const float*)d_in[24];
  const float* gain_b = (const float*)d_in[25];
  float* out = (float*)d_out;

  // Kernel A: 4*512*8 = 16384 blocks (s,n,b); stages x_attn f32 into x_out slot
  attn_kernel<<<dim3(16384), dim3(256), 0, stream>>>(
      x_col, lat_g, lat_b, wq, bq, wk, bk, wv, bv, wo, bo, out);
  // Kernel B: 64 groups * 256 chunks of 8 tokens = 16384 blocks
  // g = blockIdx.x >> 8 so concurrent blocks share a handful of groups (L2 reuse)
  col_kernel<<<dim3(16384), dim3(256), 0, stream>>>(
      zhp, ln_g, ln_b, up_w, up_b, down_w, down_b, post_w, post_b,
      enc_w, enc_b, pred_w, pred_b, gain_w, gain_b, out);
}

// Round 2
// 1763.564 us; speedup vs baseline: 2.1168x; 1.4033x over previous
//
#include <hip/hip_runtime.h>
#include <hip/hip_bf16.h>

// Problem dims: BS=4, N=512, Bb=8, Cc=8, D=128, H=512, DP=64, G=64
// Output element offsets (f32 elements, flat concat in return order)
constexpr long XO = 0;               // x_out   (4,512,64,128) 16777216
constexpr long ZO = 16777216;        // z       (4,512,64,64)   8388608
constexpr long ZH = 25165824;        // z_hat   (4,512,64,64)   8388608
constexpr long SO = 33554432;        // surprise(4,512,64)       131072
constexpr long KC = 33685504;        // k_cand  (...,128)      16777216
constexpr long VP = 50462720;        // v_post                 16777216
constexpr long GA = 67239936;        // gate                     131072
constexpr long QN = 67371008;        // q_nov                  16777216
constexpr long VC = 84148224;        // v_cand                 16777216
constexpr long WN = 100925440;       // w_nov                    131072

using short8 = __attribute__((ext_vector_type(8))) short;   // 8 bf16 (4 VGPRs)
using f32x4  = __attribute__((ext_vector_type(4))) float;   // MFMA C/D

#define MFMA16(a,b,c) __builtin_amdgcn_mfma_f32_16x16x32_bf16((a),(b),(c),0,0,0)

// ---- workspace layout (prepped split-bf16 transposed weights), offsets in shorts
constexpr long OFF_ENC_H  = 0L;         // [g][64][128]
constexpr long OFF_ENC_L  = 524288L;
constexpr long OFF_PRED_H = 1048576L;   // [g][64][64]
constexpr long OFF_PRED_L = 1310720L;
constexpr long OFF_GAIN_H = 1572864L;   // [g][128][64]
constexpr long OFF_GAIN_L = 2097152L;
constexpr long OFF_UP_H   = 2621440L;   // [g][512][128]
constexpr long OFF_UP_L   = 6815744L;
constexpr long OFF_DOWN_H = 11010048L;  // [g][128][512]
constexpr long OFF_DOWN_L = 15204352L;
constexpr long OFF_POST_H = 19398656L;  // [g][513][128]
constexpr long OFF_POST_L = 23601152L;
constexpr long WS_SHORTS  = 27803648L;  // * 2 bytes = 55.6 MB

__device__ __forceinline__ short f2bf(float f){
  unsigned u = __float_as_uint(f);
  u = u + 0x7fffu + ((u >> 16) & 1u);      // RNE
  return (short)(u >> 16);
}
__device__ __forceinline__ float bf2f(short s){
  return __uint_as_float(((unsigned)(unsigned short)s) << 16);
}
__device__ __forceinline__ float wred64(float v){
#pragma unroll
  for (int off = 32; off; off >>= 1) v += __shfl_xor(v, off, 64);
  return v;
}
__device__ __forceinline__ float wred32(float v){
#pragma unroll
  for (int off = 16; off; off >>= 1) v += __shfl_xor(v, off, 64);
  return v;
}
__device__ __forceinline__ float gelu_exact(float x){
  return x * 0.5f * (1.f + erff(x * 0.70710678118654752f));
}

// XOR-swizzled LDS addressing: 16B slots, slot ^= (row & mask) to break the
// "16 lanes read same column-slot of different rows" bank conflict (T2 regime).
template<int S>  // S = row stride in shorts (multiple of 8)
__device__ __forceinline__ int swz(int r, int c){
  constexpr int mask = ((S >> 3) - 1) < 15 ? ((S >> 3) - 1) : 15;
  return r * S + ((((c >> 3) ^ (r & mask)) << 3) | (c & 7));
}
template<int S>
__device__ __forceinline__ void putbf(short* ph, short* pl, int r, int c, float v){
  short h = f2bf(v);
  float lo = v - bf2f(h);
  int i = swz<S>(r, c);
  ph[i] = h; pl[i] = f2bf(lo);
}
template<int S>
__device__ __forceinline__ float getbf(const short* ph, const short* pl, int r, int c){
  int i = swz<S>(r, c);
  return bf2f(ph[i]) + bf2f(pl[i]);
}
template<int S>
__device__ __forceinline__ short8 ldfrag(const short* p, int r, int c8){
  return *(const short8*)&p[swz<S>(r, c8)];
}

// ---------------- weight prep: transpose + split fp32 -> bf16 hi/lo -----------
// src[g][K][N] -> dh/dl[g][N][K].  grid = 64 * ceil(K/32) * ceil(N/32)
__global__ __launch_bounds__(256) void prep_kernel(
    const float* __restrict__ src, short* __restrict__ dh, short* __restrict__ dl,
    int K, int N)
{
  __shared__ float tile[32][33];
  const int tK = (K + 31) >> 5, tN = (N + 31) >> 5;
  const int b = blockIdx.x;
  const int g = b / (tK * tN);
  const int rem = b % (tK * tN);
  const int k0 = (rem / tN) * 32;
  const int n0 = (rem % tN) * 32;
  const float* s = src + (long)g * K * N;
  const int c = threadIdx.x & 31, r = threadIdx.x >> 5;   // 8 rows per pass
#pragma unroll
  for (int i = 0; i < 4; ++i) {
    int k = k0 + r + i * 8, n = n0 + c;
    tile[r + i * 8][c] = (k < K && n < N) ? s[(long)k * N + n] : 0.f;
  }
  __syncthreads();
#pragma unroll
  for (int i = 0; i < 4; ++i) {
    int n = n0 + r + i * 8, k = k0 + c;
    if (n < N && k < K) {
      float v = tile[c][r + i * 8];
      short h = f2bf(v);
      long o = ((long)g * N + n) * K + k;
      dh[o] = h;
      dl[o] = f2bf(v - bf2f(h));
    }
  }
}

// ---------------- Kernel A: latent LN + 8x8 attention + wo residual ------------
__global__ __launch_bounds__(256) void attn_kernel(
    const float* __restrict__ x_col,
    const float* __restrict__ lat_g, const float* __restrict__ lat_b,
    const float* __restrict__ wq, const float* __restrict__ bq,
    const float* __restrict__ wk, const float* __restrict__ bk,
    const float* __restrict__ wv, const float* __restrict__ bv,
    const float* __restrict__ wo, const float* __restrict__ bo,
    float* __restrict__ xattn)
{
  __shared__ float xs[8][128], hs[8][128], qs[8][128], ks[8][128], vs[8][128];
  __shared__ float att[8][8];
  const int t = threadIdx.x;
  const long base = (long)blockIdx.x * 1024;

#pragma unroll
  for (int i = 0; i < 4; ++i) {
    int idx = t + i * 256;
    xs[idx >> 7][idx & 127] = x_col[base + idx];
  }
  __syncthreads();

  {
    int c = t >> 5, j = t & 31;
    float s = 0.f, ss = 0.f;
#pragma unroll
    for (int m = 0; m < 4; ++m) { float v = xs[c][j + 32 * m]; s += v; ss += v * v; }
    s = wred32(s); ss = wred32(ss);
    float mean = s * (1.f / 128.f);
    float var  = ss * (1.f / 128.f) - mean * mean;
    float rsq  = rsqrtf(var + 1e-5f);
#pragma unroll
    for (int m = 0; m < 4; ++m) {
      int idx = j + 32 * m;
      hs[c][idx] = (xs[c][idx] - mean) * rsq * lat_g[idx] + lat_b[idx];
    }
  }
  __syncthreads();

  const int e  = t & 127;
  const int c0 = (t >> 7) * 4;

  {
    float aq[4] = {0,0,0,0}, ak[4] = {0,0,0,0}, av[4] = {0,0,0,0};
    for (int kk = 0; kk < 128; ++kk) {
      float wqv = wq[kk * 128 + e];
      float wkv = wk[kk * 128 + e];
      float wvv = wv[kk * 128 + e];
#pragma unroll
      for (int c4 = 0; c4 < 4; ++c4) {
        float hv = hs[c0 + c4][kk];
        aq[c4] += hv * wqv; ak[c4] += hv * wkv; av[c4] += hv * wvv;
      }
    }
    float bqv = bq[e], bkv = bk[e], bvv = bv[e];
#pragma unroll
    for (int c4 = 0; c4 < 4; ++c4) {
      qs[c0 + c4][e] = aq[c4] + bqv;
      ks[c0 + c4][e] = ak[c4] + bkv;
      vs[c0 + c4][e] = av[c4] + bvv;
    }
  }
  __syncthreads();

  if (t < 64) {
    int c = t >> 3, e2 = t & 7;
    float acc = 0.f;
    for (int kk = 0; kk < 128; ++kk) acc += qs[c][kk] * ks[e2][kk];
    att[c][e2] = acc * 0.08838834764831845f;
  }
  __syncthreads();
  if (t < 8) {
    float mx = -1e30f;
#pragma unroll
    for (int e2 = 0; e2 < 8; ++e2) mx = fmaxf(mx, att[t][e2]);
    float sum = 0.f, ex[8];
#pragma unroll
    for (int e2 = 0; e2 < 8; ++e2) { ex[e2] = expf(att[t][e2] - mx); sum += ex[e2]; }
    float inv = 1.f / sum;
#pragma unroll
    for (int e2 = 0; e2 < 8; ++e2) att[t][e2] = ex[e2] * inv;
  }
  __syncthreads();

#pragma unroll
  for (int c4 = 0; c4 < 4; ++c4) {
    int c = c0 + c4;
    float acc = 0.f;
#pragma unroll
    for (int e2 = 0; e2 < 8; ++e2) acc += att[c][e2] * vs[e2][e];
    qs[c][e] = acc;
  }
  __syncthreads();

  {
    float ao[4] = {0,0,0,0};
    for (int kk = 0; kk < 128; ++kk) {
      float wov = wo[kk * 128 + e];
#pragma unroll
      for (int c4 = 0; c4 < 4; ++c4) ao[c4] += qs[c0 + c4][kk] * wov;
    }
    float bov = bo[e];
#pragma unroll
    for (int c4 = 0; c4 < 4; ++c4) {
      int c = c0 + c4;
      xattn[base + c * 128 + e] = xs[c][e] + ao[c4] + bov;
    }
  }
}

// ---------------- Kernel B (MFMA): everything after attention ------------------
// M=16 tokens per block, grid = 64 g * 128 chunks.  4 waves.
// All GEMMs: D = A(tokens x K) * B(K x N) via mfma_f32_16x16x32_bf16, split hi/lo
// (hi*hi + hi*lo + lo*hi; lo*lo ~2^-18 dropped).  C/D layout (m89-verified):
// col = lane&15, row = (lane>>4)*4 + reg.  A: row = lane&15; B: col = lane&15;
// k = (lane>>4)*8 + j for BOTH operands (any consistent k-bijection is valid).
__global__ __launch_bounds__(256, 2) void col_mfma(
    const float* __restrict__ zhp,
    const float* __restrict__ ln_g, const float* __restrict__ ln_b,
    const float* __restrict__ up_b, const float* __restrict__ down_b,
    const float* __restrict__ post_w, const float* __restrict__ post_b,
    const float* __restrict__ enc_b, const float* __restrict__ pred_b,
    const float* __restrict__ gain_b,
    const short* __restrict__ wsp,
    float* __restrict__ out)
{
  __shared__ __align__(16) short xsh[16 * 128], xsl[16 * 128];  // x (then x_out)
  __shared__ __align__(16) short znh[16 * 64],  znl[16 * 64];   // z
  __shared__ __align__(16) short dlh[16 * 64],  dll[16 * 64];   // delta
  __shared__ __align__(16) short hnh[16 * 128], hnl[16 * 128];  // LN*gain
  __shared__ __align__(16) short bgh[16 * 512], bgl[16 * 512];  // gelu(up)
  __shared__ float mean_s[16], rsq_s[16];

  const int t = threadIdx.x;
  const int g = blockIdx.x >> 7;         // 0..63
  const int chunk = blockIdx.x & 127;    // 0..127 (16 tokens each)
  const long tok0 = (long)chunk * 1024 + g;   // row for tk=0; + tk*64 per token
  const int lane = t & 63;
  const int w    = t >> 6;               // wave 0..3
  const int lr   = lane & 15;            // A-row / B-col / D-col index
  const int lg   = lane >> 4;            // k-group; D rows lg*4..lg*4+3

  // ---- P0: load x_attn (staged in XO slot), split to bf16 hi/lo --------------
#pragma unroll
  for (int i = 0; i < 2; ++i) {
    int idx = t + i * 256;               // 0..511 float4 units
    int tk = idx >> 5;
    int o4 = (idx & 31) * 4;
    float4 v = *(const float4*)&out[(tok0 + (long)tk * 64) * 128 + o4];
    putbf<128>(xsh, xsl, tk, o4 + 0, v.x);
    putbf<128>(xsh, xsl, tk, o4 + 1, v.y);
    putbf<128>(xsh, xsl, tk, o4 + 2, v.z);
    putbf<128>(xsh, xsl, tk, o4 + 3, v.w);
  }
  __syncthreads();

  // ---- P0b: LN stats per token (consumed in gain epilogue, after P1 barrier) -
  {
    int tk = t >> 4, j = t & 15;
    float s = 0.f, ss = 0.f;
#pragma unroll
    for (int m = 0; m < 8; ++m) {
      float v = getbf<128>(xsh, xsl, tk, j + 16 * m);
      s += v; ss += v * v;
    }
#pragma unroll
    for (int off = 1; off < 16; off <<= 1) { s += __shfl_xor(s, off, 64); ss += __shfl_xor(ss, off, 64); }
    if (j == 0) {
      float mn = s * (1.f / 128.f);
      float var = ss * (1.f / 128.f) - mn * mn;
      mean_s[tk] = mn; rsq_s[tk] = rsqrtf(var + 1e-5f);
    }
  }

  // ---- P1: enc GEMM (128->64): wave w owns col-tile w -----------------------
  {
    const int n = w * 16 + lr;
    const short* bh = wsp + OFF_ENC_H + ((long)g * 64 + n) * 128;
    const short* bl = wsp + OFF_ENC_L + ((long)g * 64 + n) * 128;
    f32x4 acc = {0.f, 0.f, 0.f, 0.f};
#pragma unroll
    for (int ks = 0; ks < 4; ++ks) {
      int k0 = ks * 32 + lg * 8;
      short8 ah = ldfrag<128>(xsh, lr, k0);
      short8 al = ldfrag<128>(xsl, lr, k0);
      short8 wh = *(const short8*)&bh[k0];
      short8 wl = *(const short8*)&bl[k0];
      acc = MFMA16(ah, wh, acc);
      acc = MFMA16(ah, wl, acc);
      acc = MFMA16(al, wh, acc);
    }
    float be = enc_b[g * 64 + n];
#pragma unroll
    for (int reg = 0; reg < 4; ++reg) {
      int tk = lg * 4 + reg;
      long row = tok0 + (long)tk * 64;
      float z = acc[reg] + be;
      out[ZO + row * 64 + n] = z;
      float d = z - zhp[row * 64 + n];
      putbf<64>(znh, znl, tk, n, z);
      putbf<64>(dlh, dll, tk, n, d);
    }
  }
  __syncthreads();

  // ---- P2 region: surprise/gate + pred GEMM + gain GEMM ---------------------
  {
    int tk = t >> 4, j = t & 15;
    float s = 0.f;
#pragma unroll
    for (int m = 0; m < 4; ++m) {
      float d = getbf<64>(dlh, dll, tk, j * 4 + m);
      s += d * d;
    }
#pragma unroll
    for (int off = 1; off < 16; off <<= 1) s += __shfl_xor(s, off, 64);
    if (j == 0) {
      float sur = sqrtf(s);
      out[SO + tok0 + tk * 64] = sur;
      out[GA + tok0 + tk * 64] = fminf(sur, 1.f);
    }
  }
  {
    // pred (64->64): wave w owns col-tile w
    const int n = w * 16 + lr;
    const short* bh = wsp + OFF_PRED_H + ((long)g * 64 + n) * 64;
    const short* bl = wsp + OFF_PRED_L + ((long)g * 64 + n) * 64;
    f32x4 acc = {0.f, 0.f, 0.f, 0.f};
#pragma unroll
    for (int ks = 0; ks < 2; ++ks) {
      int k0 = ks * 32 + lg * 8;
      short8 ah = ldfrag<64>(znh, lr, k0);
      short8 al = ldfrag<64>(znl, lr, k0);
      short8 wh = *(const short8*)&bh[k0];
      short8 wl = *(const short8*)&bl[k0];
      acc = MFMA16(ah, wh, acc);
      acc = MFMA16(ah, wl, acc);
      acc = MFMA16(al, wh, acc);
    }
    float bp = pred_b[g * 64 + n];
#pragma unroll
    for (int reg = 0; reg < 4; ++reg) {
      long row = tok0 + (long)(lg * 4 + reg) * 64;
      out[ZH + row * 64 + n] = acc[reg] + bp;
    }
  }
  {
    // gain (64->128): wave w owns col-tiles 2w, 2w+1; epilogue builds hn = LN*gain
    f32x4 acc2[2] = {{0.f,0.f,0.f,0.f},{0.f,0.f,0.f,0.f}};
#pragma unroll
    for (int ks = 0; ks < 2; ++ks) {
      int k0 = ks * 32 + lg * 8;
      short8 ah = ldfrag<64>(dlh, lr, k0);
      short8 al = ldfrag<64>(dll, lr, k0);
#pragma unroll
      for (int tt = 0; tt < 2; ++tt) {
        int n = (2 * w + tt) * 16 + lr;
        const short* bh = wsp + OFF_GAIN_H + ((long)g * 128 + n) * 64;
        const short* bl = wsp + OFF_GAIN_L + ((long)g * 128 + n) * 64;
        short8 wh = *(const short8*)&bh[k0];
        short8 wl = *(const short8*)&bl[k0];
        acc2[tt] = MFMA16(ah, wh, acc2[tt]);
        acc2[tt] = MFMA16(ah, wl, acc2[tt]);
        acc2[tt] = MFMA16(al, wh, acc2[tt]);
      }
    }
#pragma unroll
    for (int tt = 0; tt < 2; ++tt) {
      int n = (2 * w + tt) * 16 + lr;
      float gb = gain_b[g * 128 + n];
      float lg_ = ln_g[g * 128 + n], lb_ = ln_b[g * 128 + n];
#pragma unroll
      for (int reg = 0; reg < 4; ++reg) {
        int tk = lg * 4 + reg;
        float gain = 1.f + 0.1f * tanhf(acc2[tt][reg] + gb);
        float x = getbf<128>(xsh, xsl, tk, n);
        float ln = (x - mean_s[tk]) * rsq_s[tk] * lg_ + lb_;
        putbf<128>(hnh, hnl, tk, n, ln * gain);
      }
    }
  }
  __syncthreads();

  // ---- P4: up GEMM (128->512) + GELU ----------------------------------------
  {
    f32x4 acc8[8] = {{0.f,0.f,0.f,0.f},{0.f,0.f,0.f,0.f},{0.f,0.f,0.f,0.f},{0.f,0.f,0.f,0.f},
                     {0.f,0.f,0.f,0.f},{0.f,0.f,0.f,0.f},{0.f,0.f,0.f,0.f},{0.f,0.f,0.f,0.f}};
    const short* bh0 = wsp + OFF_UP_H + ((long)g * 512 + 8 * w * 16 + lr) * 128;
    const short* bl0 = wsp + OFF_UP_L + ((long)g * 512 + 8 * w * 16 + lr) * 128;
#pragma unroll
    for (int ks = 0; ks < 4; ++ks) {
      int k0 = ks * 32 + lg * 8;
      short8 ah = ldfrag<128>(hnh, lr, k0);
      short8 al = ldfrag<128>(hnl, lr, k0);
#pragma unroll
      for (int tt = 0; tt < 8; ++tt) {
        short8 wh = *(const short8*)&bh0[(long)tt * 2048 + k0];
        short8 wl = *(const short8*)&bl0[(long)tt * 2048 + k0];
        acc8[tt] = MFMA16(ah, wh, acc8[tt]);
        acc8[tt] = MFMA16(ah, wl, acc8[tt]);
        acc8[tt] = MFMA16(al, wh, acc8[tt]);
      }
    }
#pragma unroll
    for (int tt = 0; tt < 8; ++tt) {
      int n = (8 * w + tt) * 16 + lr;
      float ub = up_b[g * 512 + n];
#pragma unroll
      for (int reg = 0; reg < 4; ++reg) {
        int tk = lg * 4 + reg;
        putbf<512>(bgh, bgl, tk, n, gelu_exact(acc8[tt][reg] + ub));
      }
    }
  }
  __syncthreads();

  // ---- P5: down GEMM (512->128), residual, write x_out, update xs -----------
  {
    f32x4 acc2[2] = {{0.f,0.f,0.f,0.f},{0.f,0.f,0.f,0.f}};
    const short* bh0 = wsp + OFF_DOWN_H + ((long)g * 128 + 2 * w * 16 + lr) * 512;
    const short* bl0 = wsp + OFF_DOWN_L + ((long)g * 128 + 2 * w * 16 + lr) * 512;
#pragma unroll
    for (int ks = 0; ks < 16; ++ks) {
      int k0 = ks * 32 + lg * 8;
      short8 ah = ldfrag<512>(bgh, lr, k0);
      short8 al = ldfrag<512>(bgl, lr, k0);
#pragma unroll
      for (int tt = 0; tt < 2; ++tt) {
        short8 wh = *(const short8*)&bh0[(long)tt * 8192 + k0];
        short8 wl = *(const short8*)&bl0[(long)tt * 8192 + k0];
        acc2[tt] = MFMA16(ah, wh, acc2[tt]);
        acc2[tt] = MFMA16(ah, wl, acc2[tt]);
        acc2[tt] = MFMA16(al, wh, acc2[tt]);
      }
    }
#pragma unroll
    for (int tt = 0; tt < 2; ++tt) {
      int n = (2 * w + tt) * 16 + lr;
      float db = down_b[g * 128 + n];
#pragma unroll
      for (int reg = 0; reg < 4; ++reg) {
        int tk = lg * 4 + reg;
        float v = getbf<128>(xsh, xsl, tk, n) + acc2[tt][reg] + db;
        out[XO + (tok0 + (long)tk * 64) * 128 + n] = v;
        putbf<128>(xsh, xsl, tk, n, v);          // x_out becomes post input
      }
    }
  }
  __syncthreads();

  // ---- P6: post GEMM (128->512) + per-wave slice epilogue + nov column ------
  {
    f32x4 acc8[8] = {{0.f,0.f,0.f,0.f},{0.f,0.f,0.f,0.f},{0.f,0.f,0.f,0.f},{0.f,0.f,0.f,0.f},
                     {0.f,0.f,0.f,0.f},{0.f,0.f,0.f,0.f},{0.f,0.f,0.f,0.f},{0.f,0.f,0.f,0.f}};
    const short* bh0 = wsp + OFF_POST_H + ((long)g * 513 + 8 * w * 16 + lr) * 128;
    const short* bl0 = wsp + OFF_POST_L + ((long)g * 513 + 8 * w * 16 + lr) * 128;
#pragma unroll
    for (int ks = 0; ks < 4; ++ks) {
      int k0 = ks * 32 + lg * 8;
      short8 ah = ldfrag<128>(xsh, lr, k0);
      short8 al = ldfrag<128>(xsl, lr, k0);
#pragma unroll
      for (int tt = 0; tt < 8; ++tt) {
        short8 wh = *(const short8*)&bh0[(long)tt * 2048 + k0];
        short8 wl = *(const short8*)&bl0[(long)tt * 2048 + k0];
        acc8[tt] = MFMA16(ah, wh, acc8[tt]);
        acc8[tt] = MFMA16(ah, wl, acc8[tt]);
        acc8[tt] = MFMA16(al, wh, acc8[tt]);
      }
    }
    // bias; wave w owns global cols 128w..128w+127 == exactly one output slice:
    // w0: k_pre -> k_cand (normalized); w1: v_post; w2: k_cand_raw -> q_nov; w3: v_cand
    float v[8][4];
#pragma unroll
    for (int tt = 0; tt < 8; ++tt) {
      int n = (8 * w + tt) * 16 + lr;
      float pb = post_b[g * 513 + n];
#pragma unroll
      for (int reg = 0; reg < 4; ++reg) v[tt][reg] = acc8[tt][reg] + pb;
    }
    float rs[4] = {1.f, 1.f, 1.f, 1.f};
    if (w == 0 || w == 2) {
#pragma unroll
      for (int reg = 0; reg < 4; ++reg) {
        float p = 0.f;
#pragma unroll
        for (int tt = 0; tt < 8; ++tt) p += v[tt][reg] * v[tt][reg];
#pragma unroll
        for (int off = 1; off < 16; off <<= 1) p += __shfl_xor(p, off, 64);
        rs[reg] = 1.f / fmaxf(sqrtf(p), 1e-6f);
      }
    }
    const long sb = (w == 0) ? KC : (w == 1) ? VP : (w == 2) ? QN : VC;
#pragma unroll
    for (int tt = 0; tt < 8; ++tt) {
      int lc = tt * 16 + lr;                       // slice-local col 0..127
#pragma unroll
      for (int reg = 0; reg < 4; ++reg) {
        long row = tok0 + (long)(lg * 4 + reg) * 64;
        out[sb + row * 128 + lc] = v[tt][reg] * rs[reg];
      }
    }
  }
  // nov column (post col 512) from original fp32 post_w + sigmoid
  {
    int tk = t >> 4, j = t & 15;
    const float* pw = post_w + (long)g * (128 * 513) + 512;
    float p = 0.f;
#pragma unroll
    for (int m = 0; m < 8; ++m) {
      int k = j * 8 + m;
      p += getbf<128>(xsh, xsl, tk, k) * pw[(long)k * 513];
    }
#pragma unroll
    for (int off = 1; off < 16; off <<= 1) p += __shfl_xor(p, off, 64);
    if (j == 0) {
      float nv = p + post_b[g * 513 + 512];
      out[WN + tok0 + tk * 64] = 1.f / (1.f + expf(-nv));
    }
  }
}

// ---------------- Fallback VALU col kernel (used when ws too small) -----------
__global__ __launch_bounds__(256, 4) void col_valu(
    const float* __restrict__ zhp,
    const float* __restrict__ ln_g, const float* __restrict__ ln_b,
    const float* __restrict__ up_w, const float* __restrict__ up_b,
    const float* __restrict__ down_w, const float* __restrict__ down_b,
    const float* __restrict__ post_w, const float* __restrict__ post_b,
    const float* __restrict__ enc_w, const float* __restrict__ enc_b,
    const float* __restrict__ pred_w, const float* __restrict__ pred_b,
    const float* __restrict__ gain_w, const float* __restrict__ gain_b,
    float* __restrict__ out)
{
  __shared__ float xs[8][128];
  __shared__ float zv[8][64];
  __shared__ float dl[8][64];
  __shared__ float hn[8][128];
  __shared__ float big[8][512];

  const int t = threadIdx.x;
  const int g = blockIdx.x >> 8;
  const int chunk = blockIdx.x & 255;
  const long tok0 = (long)(chunk * 8) * 64 + g;

#pragma unroll
  for (int i = 0; i < 4; ++i) {
    int idx = t + i * 256;
    int tk = idx >> 7, o = idx & 127;
    xs[tk][o] = out[(tok0 + tk * 64) * 128 + o];
  }
  __syncthreads();

  {
    const int o = t & 63, tq = t >> 6;
    const float* w = enc_w + (long)g * (128 * 64) + o;
    float bias = enc_b[g * 64 + o];
#pragma unroll
    for (int pass = 0; pass < 2; ++pass) {
      int tk = tq + pass * 4;
      float zprev = zhp[(tok0 + tk * 64) * 64 + o];
      float acc = bias;
#pragma unroll 4
      for (int kk = 0; kk < 128; ++kk) acc += xs[tk][kk] * w[kk * 64];
      zv[tk][o] = acc;
      float d = acc - zprev;
      dl[tk][o] = d;
      out[ZO + (tok0 + tk * 64) * 64 + o] = acc;
      float s2 = wred64(d * d);
      if (o == 0) {
        float sur = sqrtf(s2);
        out[SO + tok0 + tk * 64] = sur;
        out[GA + tok0 + tk * 64] = fminf(sur, 1.f);
      }
    }
  }
  {
    int tk = t >> 5, j = t & 31;
    float s = 0.f, ss = 0.f;
#pragma unroll
    for (int m = 0; m < 4; ++m) { float v = xs[tk][j + 32 * m]; s += v; ss += v * v; }
    s = wred32(s); ss = wred32(ss);
    float mean = s * (1.f / 128.f);
    float var  = ss * (1.f / 128.f) - mean * mean;
    float rsq  = rsqrtf(var + 1e-5f);
#pragma unroll
    for (int m = 0; m < 4; ++m) {
      int o = j + 32 * m;
      hn[tk][o] = (xs[tk][o] - mean) * rsq * ln_g[g * 128 + o] + ln_b[g * 128 + o];
    }
  }
  __syncthreads();

  {
    const int o = t & 63, tq = t >> 6;
    const float* w = pred_w + (long)g * (64 * 64) + o;
    float bias = pred_b[g * 64 + o];
#pragma unroll
    for (int pass = 0; pass < 2; ++pass) {
      int tk = tq + pass * 4;
      float acc = bias;
#pragma unroll 4
      for (int kk = 0; kk < 64; ++kk) acc += zv[tk][kk] * w[kk * 64];
      out[ZH + (tok0 + tk * 64) * 64 + o] = acc;
    }
  }
  {
    const int o = t & 127, tb = t >> 7;
    const float* w = gain_w + (long)g * (64 * 128) + o;
    float bias = gain_b[g * 128 + o];
    float acc[4] = {bias, bias, bias, bias};
#pragma unroll 4
    for (int kk = 0; kk < 64; ++kk) {
      float wv = w[kk * 128];
#pragma unroll
      for (int m = 0; m < 4; ++m) acc[m] += dl[tb + m * 2][kk] * wv;
    }
#pragma unroll
    for (int m = 0; m < 4; ++m)
      hn[tb + m * 2][o] *= 1.f + 0.1f * tanhf(acc[m]);
  }
  __syncthreads();

  {
    const float* w = up_w + (long)g * (128 * 512) + 2 * t;
    float b0 = up_b[g * 512 + 2 * t];
    float b1 = up_b[g * 512 + 2 * t + 1];
    float a0[8], a1[8];
#pragma unroll
    for (int tk = 0; tk < 8; ++tk) { a0[tk] = b0; a1[tk] = b1; }
#pragma unroll 4
    for (int kk = 0; kk < 128; ++kk) {
      float2 wv = *(const float2*)(w + (long)kk * 512);
#pragma unroll
      for (int tk = 0; tk < 8; ++tk) {
        float hv = hn[tk][kk];
        a0[tk] += hv * wv.x; a1[tk] += hv * wv.y;
      }
    }
#pragma unroll
    for (int tk = 0; tk < 8; ++tk) {
      float2 r; r.x = gelu_exact(a0[tk]); r.y = gelu_exact(a1[tk]);
      *(float2*)&big[tk][2 * t] = r;
    }
  }
  __syncthreads();

  {
    const int o = t & 127, th = t >> 7;
    const float* w = down_w + (long)g * (512 * 128) + o;
    float acc[4] = {0,0,0,0};
#pragma unroll 8
    for (int kk = 0; kk < 512; ++kk) {
      float wv = w[(long)kk * 128];
#pragma unroll
      for (int m = 0; m < 4; ++m) acc[m] += big[th * 4 + m][kk] * wv;
    }
    float bias = down_b[g * 128 + o];
#pragma unroll
    for (int m = 0; m < 4; ++m) {
      int tk = th * 4 + m;
      float v = xs[tk][o] + acc[m] + bias;
      xs[tk][o] = v;
      out[XO + (tok0 + tk * 64) * 128 + o] = v;
    }
  }
  __syncthreads();

  {
    const float* w = post_w + (long)g * (128 * 513);
    float b0 = post_b[g * 513 + t];
    float b1 = post_b[g * 513 + t + 256];
    float a0[8], a1[8];
#pragma unroll
    for (int tk = 0; tk < 8; ++tk) { a0[tk] = b0; a1[tk] = b1; }
#pragma unroll 4
    for (int kk = 0; kk < 128; ++kk) {
      float w0 = w[kk * 513 + t];
      float w1 = w[kk * 513 + t + 256];
#pragma unroll
      for (int tk = 0; tk < 8; ++tk) {
        float xv = xs[tk][kk];
        a0[tk] += xv * w0; a1[tk] += xv * w1;
      }
    }
#pragma unroll
    for (int tk = 0; tk < 8; ++tk) { big[tk][t] = a0[tk]; big[tk][t + 256] = a1[tk]; }
  }
  if (t < 64) {
    int tk = t >> 3, j = t & 7;
    const float* w = post_w + (long)g * (128 * 513) + 512;
    float p = 0.f;
    for (int kk = j * 16; kk < j * 16 + 16; ++kk) p += xs[tk][kk] * w[(long)kk * 513];
    p += __shfl_xor(p, 1, 64);
    p += __shfl_xor(p, 2, 64);
    p += __shfl_xor(p, 4, 64);
    if (j == 0) {
      float nv = p + post_b[g * 513 + 512];
      out[WN + tok0 + tk * 64] = 1.f / (1.f + expf(-nv));
    }
  }
  __syncthreads();

  {
    int tk = t >> 5, j = t & 31;
    float s1 = 0.f, s2 = 0.f;
#pragma unroll
    for (int m = 0; m < 4; ++m) {
      float v1 = big[tk][j + 32 * m];
      float v2 = big[tk][256 + j + 32 * m];
      s1 += v1 * v1; s2 += v2 * v2;
    }
    s1 = wred32(s1); s2 = wred32(s2);
    float i1 = 1.f / fmaxf(sqrtf(s1), 1e-6f);
    float i2 = 1.f / fmaxf(sqrtf(s2), 1e-6f);
    long ob = (tok0 + tk * 64) * 128;
#pragma unroll
    for (int m = 0; m < 4; ++m) {
      int o = j + 32 * m;
      out[KC + ob + o] = big[tk][o] * i1;
      out[VP + ob + o] = big[tk][128 + o];
      out[QN + ob + o] = big[tk][256 + o] * i2;
      out[VC + ob + o] = big[tk][384 + o];
    }
  }
}

extern "C" void kernel_launch(void* const* d_in, const int* in_sizes, int n_in,
                              void* d_out, int out_size, void* d_ws, size_t ws_size,
                              hipStream_t stream) {
  (void)in_sizes; (void)n_in; (void)out_size;
  const float* x_col  = (const float*)d_in[0];
  const float* zhp    = (const float*)d_in[1];
  const float* ln_g   = (const float*)d_in[2];
  const float* ln_b   = (const float*)d_in[3];
  const float* up_w   = (const float*)d_in[4];
  const float* up_b   = (const float*)d_in[5];
  const float* down_w = (const float*)d_in[6];
  const float* down_b = (const float*)d_in[7];
  const float* lat_g  = (const float*)d_in[8];
  const float* lat_b  = (const float*)d_in[9];
  const float* wq     = (const float*)d_in[10];
  const float* bq     = (const float*)d_in[11];
  const float* wk     = (const float*)d_in[12];
  const float* bk     = (const float*)d_in[13];
  const float* wv     = (const float*)d_in[14];
  const float* bv     = (const float*)d_in[15];
  const float* wo     = (const float*)d_in[16];
  const float* bo     = (const float*)d_in[17];
  const float* post_w = (const float*)d_in[18];
  const float* post_b = (const float*)d_in[19];
  const float* enc_w  = (const float*)d_in[20];
  const float* enc_b  = (const float*)d_in[21];
  const float* pred_w = (const float*)d_in[22];
  const float* pred_b = (const float*)d_in[23];
  const float* gain_w = (const float*)d_in[24];
  const float* gain_b = (const float*)d_in[25];
  float* out = (float*)d_out;

  attn_kernel<<<dim3(16384), dim3(256), 0, stream>>>(
      x_col, lat_g, lat_b, wq, bq, wk, bk, wv, bv, wo, bo, out);

  if (ws_size >= (size_t)(WS_SHORTS * 2)) {
    short* wsp = (short*)d_ws;
    prep_kernel<<<dim3(512),  dim3(256), 0, stream>>>(enc_w,  wsp + OFF_ENC_H,  wsp + OFF_ENC_L,  128,  64);
    prep_kernel<<<dim3(256),  dim3(256), 0, stream>>>(pred_w, wsp + OFF_PRED_H, wsp + OFF_PRED_L,  64,  64);
    prep_kernel<<<dim3(512),  dim3(256), 0, stream>>>(gain_w, wsp + OFF_GAIN_H, wsp + OFF_GAIN_L,  64, 128);
    prep_kernel<<<dim3(4096), dim3(256), 0, stream>>>(up_w,   wsp + OFF_UP_H,   wsp + OFF_UP_L,   128, 512);
    prep_kernel<<<dim3(4096), dim3(256), 0, stream>>>(down_w, wsp + OFF_DOWN_H, wsp + OFF_DOWN_L, 512, 128);
    prep_kernel<<<dim3(4352), dim3(256), 0, stream>>>(post_w, wsp + OFF_POST_H, wsp + OFF_POST_L, 128, 513);
    col_mfma<<<dim3(8192), dim3(256), 0, stream>>>(
        zhp, ln_g, ln_b, up_b, down_b, post_w, post_b,
        enc_b, pred_b, gain_b, wsp, out);
  } else {
    col_valu<<<dim3(16384), dim3(256), 0, stream>>>(
        zhp, ln_g, ln_b, up_w, up_b, down_w, down_b, post_w, post_b,
        enc_w, enc_b, pred_w, pred_b, gain_w, gain_b, out);
  }
}